// Round 6
// baseline (253.423 us; speedup 1.0000x reference)
//
#include <hip/hip_runtime.h>
#include <math.h>

#define IN_DIM   256
#define OUT_DIM  128
#define NCOEF    19          // NUM + K
#define BATCH    2048
#define BT       4           // batches per block
#define TILE_F   (IN_DIM * NCOEF)   // 4864 floats per o-tile

__device__ __forceinline__ float softplus_f(float v) {
  return (v > 20.0f) ? v : log1pf(expf(v));
}

// async global->LDS, 16B per lane (linear, lane-ordered dest)
__device__ __forceinline__ void load_lds16(const float* g, float* l) {
  __builtin_amdgcn_global_load_lds(
      (const __attribute__((address_space(1))) void*)g,
      (__attribute__((address_space(3))) void*)l,
      16, 0, 0);
}

// ---------------- prep: transform coef (monotonic rows), fold scales, transpose ----
__global__ void kan_prep(const float* __restrict__ coef,
                         const float* __restrict__ ssp,
                         const float* __restrict__ sbase,
                         const float* __restrict__ mask,
                         const float* __restrict__ bmask,
                         float* __restrict__ coefT,   // [o][i][19]
                         float* __restrict__ At,      // [o][i]
                         float* __restrict__ Bt) {    // [o][i]
  int g = blockIdx.x * 256 + threadIdx.x;   // g = o*256 + i
  int o = g >> 8;
  int i = g & 255;
  const float* src = coef + ((size_t)i * OUT_DIM + o) * NCOEF;
  float c[NCOEF];
#pragma unroll
  for (int d = 0; d < NCOEF; ++d) c[d] = src[d];
  if (i < 2) {
    // MONO = ((0,+1),(1,-1)): cumsum(softplus) with direction
    float dir = (i == 0) ? 1.0f : -1.0f;
    float acc = 0.0f;
#pragma unroll
    for (int d = 0; d < NCOEF; ++d) { acc += softplus_f(c[d]); c[d] = dir * acc; }
  }
  float* dst = coefT + (size_t)g * NCOEF;
#pragma unroll
  for (int d = 0; d < NCOEF; ++d) dst[d] = c[d];
  int io = i * OUT_DIM + o;
  float m = mask[io];
  At[g] = m * softplus_f(ssp[io]);
  Bt[g] = m * bmask[io] * sbase[io];
}

// ---------------- wave64 sum via DPP (pure VALU), result in lane 63 ----------------
__device__ __forceinline__ float wave_reduce(float v) {
  int t;
  t = __builtin_amdgcn_update_dpp(0, __float_as_int(v), 0x111, 0xf, 0xf, true); v += __int_as_float(t); // row_shr:1
  t = __builtin_amdgcn_update_dpp(0, __float_as_int(v), 0x112, 0xf, 0xf, true); v += __int_as_float(t); // row_shr:2
  t = __builtin_amdgcn_update_dpp(0, __float_as_int(v), 0x114, 0xf, 0xf, true); v += __int_as_float(t); // row_shr:4
  t = __builtin_amdgcn_update_dpp(0, __float_as_int(v), 0x118, 0xf, 0xf, true); v += __int_as_float(t); // row_shr:8
  t = __builtin_amdgcn_update_dpp(0, __float_as_int(v), 0x142, 0xa, 0xf, true); v += __int_as_float(t); // row_bcast:15 -> rows 1,3
  t = __builtin_amdgcn_update_dpp(0, __float_as_int(v), 0x143, 0xc, 0xf, true); v += __int_as_float(t); // row_bcast:31 -> rows 2,3
  return v;
}

// ---------------- main ----------------
__global__ __launch_bounds__(512, 6) void kan_main(
    const float* __restrict__ x,
    const float* __restrict__ coefT,
    const float* __restrict__ At,
    const float* __restrict__ Bt,
    float* __restrict__ out,
    float* __restrict__ preacts,
    float* __restrict__ postacts,
    float* __restrict__ postspline) {
  __shared__ __align__(16) float s_coef[2][TILE_F];   // 2 x 19456 B
  __shared__ float s_out[BT][OUT_DIM][4];             // 8 KB

  const int tid  = threadIdx.x;
  const int i    = tid & 255;
  const int bsub = tid >> 8;        // 0..1 -> handles b_local {2*bsub, 2*bsub+1}
  const int wq   = (tid >> 6) & 3;  // wave index within i-group
  const int b0   = blockIdx.x * BT;

  float xv[2], sl[2], wv[2][4];
  int   wi[2][4];

#pragma unroll
  for (int bb = 0; bb < 2; ++bb) {
    int b = b0 + bsub * 2 + bb;
    float xx = x[(size_t)b * IN_DIM + i];
    xv[bb] = xx;
    sl[bb] = xx / (1.0f + expf(-xx));          // silu

    // locate interval: knots g(a) = -1.375 + 0.125*a  (bit-exact vs reference grid)
    float tpos = (xx + 1.375f) * 8.0f;
    int j = (int)floorf(tpos);
    bool valid = (j >= 0) && (j <= 21);
    int jc = valid ? j : 3;

    // local Cox-de Boor: N[m] = B_{jc-p+m, p}(x)
    float N[4] = {1.0f, 0.0f, 0.0f, 0.0f};
#pragma unroll
    for (int p = 1; p <= 3; ++p) {
      const float inv = (p == 1) ? 8.0f : ((p == 2) ? 4.0f : (8.0f / 3.0f));
      float Np[4] = {0.0f, 0.0f, 0.0f, 0.0f};
#pragma unroll
      for (int m = 0; m < 4; ++m) {
        if (m <= p) {
          float ga = -1.375f + 0.125f * (float)(jc + m - p);
          float v = 0.0f;
          if (m > 0) v += (xx - ga) * inv * N[m - 1];
          if (m < p) v += ((ga + 0.125f * (float)(p + 1)) - xx) * inv * N[m];
          Np[m] = v;
        }
      }
#pragma unroll
      for (int m = 0; m < 4; ++m) N[m] = Np[m];
    }
#pragma unroll
    for (int r = 0; r < 4; ++r) {
      int dr = jc - 3 + r;
      bool ok = valid && (dr >= 0) && (dr <= 18);
      wv[bb][r] = ok ? N[r] : 0.0f;
      wi[bb][r] = i * NCOEF + (ok ? dr : 0);
    }
  }

  // ---- prologue: async-stage o=0 into buffer 0; prefetch scales for o=0
  {
    const float* src = coefT;            // o = 0
    float* dst = &s_coef[0][0];
    load_lds16(src + tid * 4,        dst + tid * 4);
    load_lds16(src + 2048 + tid * 4, dst + 2048 + tid * 4);
    if (tid < 192) load_lds16(src + 4096 + tid * 4, dst + 4096 + tid * 4);
  }
  float a_cur = At[i];
  float b_cur = Bt[i];
  __syncthreads();   // full drain once in prologue: staged loads landed

  size_t off0 = ((size_t)(b0 + bsub * 2)     * OUT_DIM) * IN_DIM + i;
  size_t off1 = ((size_t)(b0 + bsub * 2 + 1) * OUT_DIM) * IN_DIM + i;

#pragma unroll 2
  for (int o = 0; o < OUT_DIM; ++o) {
    const int cur = o & 1;
    const float* sc = &s_coef[cur][0];

    // ---- issue next tile's async stage FIRST (latency hides under compute)
    if (o + 1 < OUT_DIM) {
      const float* src = coefT + (size_t)(o + 1) * TILE_F;
      float* dst = &s_coef[cur ^ 1][0];
      load_lds16(src + tid * 4,        dst + tid * 4);
      load_lds16(src + 2048 + tid * 4, dst + 2048 + tid * 4);
      if (tid < 192) load_lds16(src + 4096 + tid * 4, dst + 4096 + tid * 4);
    }
    // pin staging issues before everything that follows (keeps them oldest in VMEM FIFO)
    asm volatile("" ::: "memory");

    float a_nxt = 0.0f, b_nxt = 0.0f;
    if (o + 1 < OUT_DIM) {
      a_nxt = At[(o + 1) * IN_DIM + i];
      b_nxt = Bt[(o + 1) * IN_DIM + i];
    }

#pragma unroll
    for (int bb = 0; bb < 2; ++bb) {
      int bl = bsub * 2 + bb;
      float sp = wv[bb][0] * sc[wi[bb][0]]
               + wv[bb][1] * sc[wi[bb][1]]
               + wv[bb][2] * sc[wi[bb][2]]
               + wv[bb][3] * sc[wi[bb][3]];
      float ya = a_cur * sp + b_cur * sl[bb];

      size_t off = (bb == 0 ? off0 : off1) + (size_t)o * IN_DIM;
      // A/B vs R3: PLAIN stores (drop nontemporal) — single-variable test
      postspline[off] = sp;
      postacts[off]   = ya;
      preacts[off]    = xv[bb];

      float red = wave_reduce(ya);
      if ((tid & 63) == 63) s_out[bl][o][wq] = red;
    }

    // ---- counted wait: force the 3 lds-loads (+scale loads, +prev-iter stores)
    // complete while leaving THIS iteration's 6 stores in flight. Never vmcnt(0).
    asm volatile("s_waitcnt vmcnt(6)" ::: "memory");
    __builtin_amdgcn_s_barrier();

    a_cur = a_nxt;
    b_cur = b_nxt;
  }

  __syncthreads();   // full drain once in epilogue (s_out ds_writes)
  {
    int bl = tid >> 7;       // 0..3
    int o  = tid & 127;
    float s = s_out[bl][o][0] + s_out[bl][o][1] + s_out[bl][o][2] + s_out[bl][o][3];
    out[(size_t)(b0 + bl) * OUT_DIM + o] = s;
  }
}

extern "C" void kernel_launch(void* const* d_in, const int* in_sizes, int n_in,
                              void* d_out, int out_size, void* d_ws, size_t ws_size,
                              hipStream_t stream) {
  (void)in_sizes; (void)n_in; (void)out_size; (void)ws_size;

  const float* x     = (const float*)d_in[0];
  const float* coef  = (const float*)d_in[1];
  const float* ssp   = (const float*)d_in[2];
  const float* sbase = (const float*)d_in[3];
  // d_in[4] = grid (analytic knots are bit-identical; unused)
  const float* mask  = (const float*)d_in[5];
  const float* bmask = (const float*)d_in[6];

  float* coefT = (float*)d_ws;                                   // 622592 f
  float* At    = coefT + (size_t)OUT_DIM * IN_DIM * NCOEF;       // 32768 f
  float* Bt    = At + (size_t)OUT_DIM * IN_DIM;                  // 32768 f

  float* out        = (float*)d_out;
  float* preacts    = out + (size_t)BATCH * OUT_DIM;
  float* postacts   = preacts + (size_t)BATCH * OUT_DIM * IN_DIM;
  float* postspline = postacts + (size_t)BATCH * OUT_DIM * IN_DIM;

  kan_prep<<<(OUT_DIM * IN_DIM) / 256, 256, 0, stream>>>(coef, ssp, sbase, mask, bmask,
                                                         coefT, At, Bt);
  kan_main<<<BATCH / BT, 512, 0, stream>>>(x, coefT, At, Bt,
                                           out, preacts, postacts, postspline);
}

// Round 8
// 207.011 us; speedup vs baseline: 1.2242x; 1.2242x over previous
//
#include <hip/hip_runtime.h>
#include <math.h>

#define IN_DIM   256
#define OUT_DIM  128
#define NCOEF    19                 // NUM + K
#define BATCH    2048
#define BT       4                  // batches per block (one per wave)
#define QSTRIDE  77                 // padded quad stride in dwords; odd -> conflict-free
#define TILE_F   (64 * QSTRIDE)     // 4928 floats per o-tile (19712 B)

typedef float f32x4 __attribute__((ext_vector_type(4)));

__device__ __forceinline__ float softplus_f(float v) {
  return (v > 20.0f) ? v : log1pf(expf(v));
}

// async global->LDS, 16B per lane (linear, lane-ordered dest)
__device__ __forceinline__ void load_lds16(const float* g, float* l) {
  __builtin_amdgcn_global_load_lds(
      (const __attribute__((address_space(1))) void*)g,
      (__attribute__((address_space(3))) void*)l,
      16, 0, 0);
}

// stage one 4928-float o-tile with 256 threads (5 x 16B, tail overlaps: all lanes active)
__device__ __forceinline__ void stage_tile(const float* src, float* dst, int tid) {
  load_lds16(src + tid * 4,        dst + tid * 4);
  load_lds16(src + 1024 + tid * 4, dst + 1024 + tid * 4);
  load_lds16(src + 2048 + tid * 4, dst + 2048 + tid * 4);
  load_lds16(src + 3072 + tid * 4, dst + 3072 + tid * 4);
  load_lds16(src + 3904 + tid * 4, dst + 3904 + tid * 4);  // overlapped tail (benign rewrite)
}

// ---------------- prep: monotonic rows, fold scales, transpose + quad-pad swizzle ----
__global__ void kan_prep(const float* __restrict__ coef,
                         const float* __restrict__ ssp,
                         const float* __restrict__ sbase,
                         const float* __restrict__ mask,
                         const float* __restrict__ bmask,
                         float* __restrict__ coefT,   // [o][quad q][4 rows x 19 + pad]
                         float* __restrict__ At,      // [o][i]
                         float* __restrict__ Bt) {    // [o][i]
  int g = blockIdx.x * 256 + threadIdx.x;   // g = o*256 + i
  int o = g >> 8;
  int i = g & 255;
  const float* src = coef + ((size_t)i * OUT_DIM + o) * NCOEF;
  float c[NCOEF];
#pragma unroll
  for (int d = 0; d < NCOEF; ++d) c[d] = src[d];
  if (i < 2) {
    // MONO = ((0,+1),(1,-1)): cumsum(softplus) with direction
    float dir = (i == 0) ? 1.0f : -1.0f;
    float acc = 0.0f;
#pragma unroll
    for (int d = 0; d < NCOEF; ++d) { acc += softplus_f(c[d]); c[d] = dir * acc; }
  }
  float* dst = coefT + (size_t)o * TILE_F + (i >> 2) * QSTRIDE + (i & 3) * NCOEF;
#pragma unroll
  for (int d = 0; d < NCOEF; ++d) dst[d] = c[d];
  if ((i & 3) == 3) dst[NCOEF] = 0.0f;     // pad slot 76 of the quad
  int io = i * OUT_DIM + o;
  float m = mask[io];
  At[g] = m * softplus_f(ssp[io]);
  Bt[g] = m * bmask[io] * sbase[io];
}

// ---------------- wave64 sum via DPP (pure VALU), result in lane 63 ----------------
__device__ __forceinline__ float wave_reduce(float v) {
  int t;
  t = __builtin_amdgcn_update_dpp(0, __float_as_int(v), 0x111, 0xf, 0xf, true); v += __int_as_float(t); // row_shr:1
  t = __builtin_amdgcn_update_dpp(0, __float_as_int(v), 0x112, 0xf, 0xf, true); v += __int_as_float(t); // row_shr:2
  t = __builtin_amdgcn_update_dpp(0, __float_as_int(v), 0x114, 0xf, 0xf, true); v += __int_as_float(t); // row_shr:4
  t = __builtin_amdgcn_update_dpp(0, __float_as_int(v), 0x118, 0xf, 0xf, true); v += __int_as_float(t); // row_shr:8
  t = __builtin_amdgcn_update_dpp(0, __float_as_int(v), 0x142, 0xa, 0xf, true); v += __int_as_float(t); // row_bcast:15 -> rows 1,3
  t = __builtin_amdgcn_update_dpp(0, __float_as_int(v), 0x143, 0xc, 0xf, true); v += __int_as_float(t); // row_bcast:31 -> rows 2,3
  return v;
}

// ---------------- main: 4 i per lane, float4 stores, wave = one batch ----------------
__global__ __launch_bounds__(256, 2) void kan_main(
    const float* __restrict__ x,
    const float* __restrict__ coefT,
    const float* __restrict__ At,
    const float* __restrict__ Bt,
    float* __restrict__ out,
    float* __restrict__ preacts,
    float* __restrict__ postacts,
    float* __restrict__ postspline) {
  __shared__ __align__(16) float s_coef[2][TILE_F];   // 2 x 19712 B

  const int tid  = threadIdx.x;
  const int lane = tid & 63;          // quad index: rows 4*lane .. 4*lane+3
  const int w    = tid >> 6;          // wave 0..3 -> batch
  const int b    = blockIdx.x * BT + w;
  const int i0   = lane * 4;

  const f32x4 xv4 = *(const f32x4*)(x + (size_t)b * IN_DIM + i0);
  float xv[4] = {xv4.x, xv4.y, xv4.z, xv4.w};
  float sl[4], wv[4][4];
  int   wl[4][4];

#pragma unroll
  for (int rr = 0; rr < 4; ++rr) {
    float xx = xv[rr];
    sl[rr] = xx / (1.0f + expf(-xx));          // silu

    // locate interval: knots g(a) = -1.375 + 0.125*a  (bit-exact vs reference grid)
    float tpos = (xx + 1.375f) * 8.0f;
    int j = (int)floorf(tpos);
    bool valid = (j >= 0) && (j <= 21);
    int jc = valid ? j : 3;

    // local Cox-de Boor: N[m] = B_{jc-p+m, p}(x)
    float N[4] = {1.0f, 0.0f, 0.0f, 0.0f};
#pragma unroll
    for (int p = 1; p <= 3; ++p) {
      const float inv = (p == 1) ? 8.0f : ((p == 2) ? 4.0f : (8.0f / 3.0f));
      float Np[4] = {0.0f, 0.0f, 0.0f, 0.0f};
#pragma unroll
      for (int m = 0; m < 4; ++m) {
        if (m <= p) {
          float ga = -1.375f + 0.125f * (float)(jc + m - p);
          float v = 0.0f;
          if (m > 0) v += (xx - ga) * inv * N[m - 1];
          if (m < p) v += ((ga + 0.125f * (float)(p + 1)) - xx) * inv * N[m];
          Np[m] = v;
        }
      }
#pragma unroll
      for (int m = 0; m < 4; ++m) N[m] = Np[m];
    }
#pragma unroll
    for (int r = 0; r < 4; ++r) {
      int dr = jc - 3 + r;
      bool ok = valid && (dr >= 0) && (dr <= 18);
      wv[rr][r] = ok ? N[r] : 0.0f;
      wl[rr][r] = lane * QSTRIDE + rr * NCOEF + (ok ? dr : 0);
    }
  }

  // ---- prologue: async-stage o=0 into buffer 0; prefetch scales for o=0
  stage_tile(coefT, &s_coef[0][0], tid);
  f32x4 a4 = *(const f32x4*)(At + i0);
  f32x4 b4 = *(const f32x4*)(Bt + i0);
  __syncthreads();   // full drain once in prologue: staged tile landed

  const size_t obase = ((size_t)b * OUT_DIM) * IN_DIM + i0;

#pragma unroll 2
  for (int o = 0; o < OUT_DIM; ++o) {
    const float* sc = &s_coef[o & 1][0];

    // ---- issue next tile's async stage FIRST (latency hides under compute+stores)
    if (o + 1 < OUT_DIM)
      stage_tile(coefT + (size_t)(o + 1) * TILE_F, &s_coef[(o & 1) ^ 1][0], tid);
    asm volatile("" ::: "memory");   // pin staging issues oldest in VMEM FIFO

    f32x4 a4n = a4, b4n = b4;
    if (o + 1 < OUT_DIM) {
      a4n = *(const f32x4*)(At + (o + 1) * IN_DIM + i0);
      b4n = *(const f32x4*)(Bt + (o + 1) * IN_DIM + i0);
    }

    float sp[4], ya[4];
#pragma unroll
    for (int rr = 0; rr < 4; ++rr) {
      sp[rr] = wv[rr][0] * sc[wl[rr][0]] + wv[rr][1] * sc[wl[rr][1]]
             + wv[rr][2] * sc[wl[rr][2]] + wv[rr][3] * sc[wl[rr][3]];
    }
    ya[0] = a4.x * sp[0] + b4.x * sl[0];
    ya[1] = a4.y * sp[1] + b4.y * sl[1];
    ya[2] = a4.z * sp[2] + b4.z * sl[2];
    ya[3] = a4.w * sp[3] + b4.w * sl[3];

    size_t off = obase + (size_t)o * IN_DIM;
    f32x4 sp4 = {sp[0], sp[1], sp[2], sp[3]};
    f32x4 ya4 = {ya[0], ya[1], ya[2], ya[3]};
    __builtin_nontemporal_store(sp4, (f32x4*)(postspline + off));
    __builtin_nontemporal_store(ya4, (f32x4*)(postacts + off));
    __builtin_nontemporal_store(xv4, (f32x4*)(preacts + off));

    float red = wave_reduce((ya[0] + ya[1]) + (ya[2] + ya[3]));
    if (lane == 63) out[(size_t)b * OUT_DIM + o] = red;

    // counted wait: 5 stage + 2 scale loads (+prev stores) complete; leave this
    // iteration's 3 stores in flight. Never vmcnt(0) in the loop.
    asm volatile("s_waitcnt vmcnt(4)" ::: "memory");
    __builtin_amdgcn_s_barrier();

    a4 = a4n; b4 = b4n;
  }
}

extern "C" void kernel_launch(void* const* d_in, const int* in_sizes, int n_in,
                              void* d_out, int out_size, void* d_ws, size_t ws_size,
                              hipStream_t stream) {
  (void)in_sizes; (void)n_in; (void)out_size; (void)ws_size;

  const float* x     = (const float*)d_in[0];
  const float* coef  = (const float*)d_in[1];
  const float* ssp   = (const float*)d_in[2];
  const float* sbase = (const float*)d_in[3];
  // d_in[4] = grid (analytic knots are bit-identical; unused)
  const float* mask  = (const float*)d_in[5];
  const float* bmask = (const float*)d_in[6];

  float* coefT = (float*)d_ws;                                   // 128*4928 = 630784 f
  float* At    = coefT + (size_t)OUT_DIM * TILE_F;               // 32768 f
  float* Bt    = At + (size_t)OUT_DIM * IN_DIM;                  // 32768 f

  float* out        = (float*)d_out;
  float* preacts    = out + (size_t)BATCH * OUT_DIM;
  float* postacts   = preacts + (size_t)BATCH * OUT_DIM * IN_DIM;
  float* postspline = postacts + (size_t)BATCH * OUT_DIM * IN_DIM;

  kan_prep<<<(OUT_DIM * IN_DIM) / 256, 256, 0, stream>>>(coef, ssp, sbase, mask, bmask,
                                                         coefT, At, Bt);
  kan_main<<<BATCH / BT, 256, 0, stream>>>(x, coefT, At, Bt,
                                           out, preacts, postacts, postspline);
}

// Round 9
// 206.993 us; speedup vs baseline: 1.2243x; 1.0001x over previous
//
#include <hip/hip_runtime.h>
#include <math.h>

#define IN_DIM   256
#define OUT_DIM  128
#define NCOEF    19          // NUM + K
#define BATCH    2048
#define BT       4           // batches per block
#define TILE_F   (IN_DIM * NCOEF)   // 4864 floats per o-tile

__device__ __forceinline__ float softplus_f(float v) {
  return (v > 20.0f) ? v : log1pf(expf(v));
}

// async global->LDS, 16B per lane (linear, lane-ordered dest)
__device__ __forceinline__ void load_lds16(const float* g, float* l) {
  __builtin_amdgcn_global_load_lds(
      (const __attribute__((address_space(1))) void*)g,
      (__attribute__((address_space(3))) void*)l,
      16, 0, 0);
}

// stage one o-tile (4864 floats) with 512 threads: 3 x 16B (last partially masked)
__device__ __forceinline__ void stage_tile(const float* src, float* dst, int tid) {
  load_lds16(src + tid * 4,        dst + tid * 4);
  load_lds16(src + 2048 + tid * 4, dst + 2048 + tid * 4);
  if (tid < 192) load_lds16(src + 4096 + tid * 4, dst + 4096 + tid * 4);
}

// ---------------- prep: transform coef (monotonic rows), fold scales, transpose ----
__global__ void kan_prep(const float* __restrict__ coef,
                         const float* __restrict__ ssp,
                         const float* __restrict__ sbase,
                         const float* __restrict__ mask,
                         const float* __restrict__ bmask,
                         float* __restrict__ coefT,   // [o][i][19]
                         float* __restrict__ At,      // [o][i]
                         float* __restrict__ Bt) {    // [o][i]
  int g = blockIdx.x * 256 + threadIdx.x;   // g = o*256 + i
  int o = g >> 8;
  int i = g & 255;
  const float* src = coef + ((size_t)i * OUT_DIM + o) * NCOEF;
  float c[NCOEF];
#pragma unroll
  for (int d = 0; d < NCOEF; ++d) c[d] = src[d];
  if (i < 2) {
    // MONO = ((0,+1),(1,-1)): cumsum(softplus) with direction
    float dir = (i == 0) ? 1.0f : -1.0f;
    float acc = 0.0f;
#pragma unroll
    for (int d = 0; d < NCOEF; ++d) { acc += softplus_f(c[d]); c[d] = dir * acc; }
  }
  float* dst = coefT + (size_t)g * NCOEF;
#pragma unroll
  for (int d = 0; d < NCOEF; ++d) dst[d] = c[d];
  int io = i * OUT_DIM + o;
  float m = mask[io];
  At[g] = m * softplus_f(ssp[io]);
  Bt[g] = m * bmask[io] * sbase[io];
}

// ---------------- wave64 sum via DPP (pure VALU), result in lane 63 ----------------
__device__ __forceinline__ float wave_reduce(float v) {
  int t;
  t = __builtin_amdgcn_update_dpp(0, __float_as_int(v), 0x111, 0xf, 0xf, true); v += __int_as_float(t); // row_shr:1
  t = __builtin_amdgcn_update_dpp(0, __float_as_int(v), 0x112, 0xf, 0xf, true); v += __int_as_float(t); // row_shr:2
  t = __builtin_amdgcn_update_dpp(0, __float_as_int(v), 0x114, 0xf, 0xf, true); v += __int_as_float(t); // row_shr:4
  t = __builtin_amdgcn_update_dpp(0, __float_as_int(v), 0x118, 0xf, 0xf, true); v += __int_as_float(t); // row_shr:8
  t = __builtin_amdgcn_update_dpp(0, __float_as_int(v), 0x142, 0xa, 0xf, true); v += __int_as_float(t); // row_bcast:15 -> rows 1,3
  t = __builtin_amdgcn_update_dpp(0, __float_as_int(v), 0x143, 0xc, 0xf, true); v += __int_as_float(t); // row_bcast:31 -> rows 2,3
  return v;
}

// ---------------- main: depth-2 pipeline (triple-buffered LDS) ----------------
__global__ __launch_bounds__(512, 4) void kan_main(
    const float* __restrict__ x,
    const float* __restrict__ coefT,
    const float* __restrict__ At,
    const float* __restrict__ Bt,
    float* __restrict__ out,
    float* __restrict__ preacts,
    float* __restrict__ postacts,
    float* __restrict__ postspline) {
  __shared__ __align__(16) float s_coef[3][TILE_F];   // 3 x 19456 B
  __shared__ float s_out[BT][OUT_DIM][4];             // 8 KB

  const int tid  = threadIdx.x;
  const int i    = tid & 255;
  const int bsub = tid >> 8;        // 0..1 -> handles b_local {2*bsub, 2*bsub+1}
  const int wq   = (tid >> 6) & 3;  // wave index within i-group
  const int b0   = blockIdx.x * BT;

  float xv[2], sl[2], wv[2][4];
  int   wi[2][4];

#pragma unroll
  for (int bb = 0; bb < 2; ++bb) {
    int b = b0 + bsub * 2 + bb;
    float xx = x[(size_t)b * IN_DIM + i];
    xv[bb] = xx;
    sl[bb] = xx / (1.0f + expf(-xx));          // silu

    // locate interval: knots g(a) = -1.375 + 0.125*a  (bit-exact vs reference grid)
    float tpos = (xx + 1.375f) * 8.0f;
    int j = (int)floorf(tpos);
    bool valid = (j >= 0) && (j <= 21);
    int jc = valid ? j : 3;

    // local Cox-de Boor: N[m] = B_{jc-p+m, p}(x)
    float N[4] = {1.0f, 0.0f, 0.0f, 0.0f};
#pragma unroll
    for (int p = 1; p <= 3; ++p) {
      const float inv = (p == 1) ? 8.0f : ((p == 2) ? 4.0f : (8.0f / 3.0f));
      float Np[4] = {0.0f, 0.0f, 0.0f, 0.0f};
#pragma unroll
      for (int m = 0; m < 4; ++m) {
        if (m <= p) {
          float ga = -1.375f + 0.125f * (float)(jc + m - p);
          float v = 0.0f;
          if (m > 0) v += (xx - ga) * inv * N[m - 1];
          if (m < p) v += ((ga + 0.125f * (float)(p + 1)) - xx) * inv * N[m];
          Np[m] = v;
        }
      }
#pragma unroll
      for (int m = 0; m < 4; ++m) N[m] = Np[m];
    }
#pragma unroll
    for (int r = 0; r < 4; ++r) {
      int dr = jc - 3 + r;
      bool ok = valid && (dr >= 0) && (dr <= 18);
      wv[bb][r] = ok ? N[r] : 0.0f;
      wi[bb][r] = i * NCOEF + (ok ? dr : 0);
    }
  }

  // ---- prologue: stage o=0,1; prefetch scales for o=0,1
  stage_tile(coefT,          &s_coef[0][0], tid);
  stage_tile(coefT + TILE_F, &s_coef[1][0], tid);
  float a_cur = At[i],             b_cur = Bt[i];
  float a_nx1 = At[IN_DIM + i],    b_nx1 = Bt[IN_DIM + i];
  __syncthreads();   // full drain once in prologue

  size_t off0 = ((size_t)(b0 + bsub * 2)     * OUT_DIM) * IN_DIM + i;
  size_t off1 = ((size_t)(b0 + bsub * 2 + 1) * OUT_DIM) * IN_DIM + i;

#pragma unroll 3
  for (int o = 0; o < OUT_DIM; ++o) {
    const float* sc = &s_coef[o % 3][0];

    // ---- issue stage for o+2 (two iterations of cover; dead-buffer rewrite at tail)
    {
      const int on = (o + 2 < OUT_DIM) ? o + 2 : OUT_DIM - 1;
      stage_tile(coefT + (size_t)on * TILE_F, &s_coef[(o + 2) % 3][0], tid);
      asm volatile("" ::: "memory");   // pin staging issues oldest among this iter's VMEM
      float a_nx2 = At[on * IN_DIM + i];
      float b_nx2 = Bt[on * IN_DIM + i];

#pragma unroll
      for (int bb = 0; bb < 2; ++bb) {
        int bl = bsub * 2 + bb;
        float sp = wv[bb][0] * sc[wi[bb][0]]
                 + wv[bb][1] * sc[wi[bb][1]]
                 + wv[bb][2] * sc[wi[bb][2]]
                 + wv[bb][3] * sc[wi[bb][3]];
        float ya = a_cur * sp + b_cur * sl[bb];

        size_t off = (bb == 0 ? off0 : off1) + (size_t)o * IN_DIM;
        __builtin_nontemporal_store(sp,     postspline + off);
        __builtin_nontemporal_store(ya,     postacts   + off);
        __builtin_nontemporal_store(xv[bb], preacts    + off);

        float red = wave_reduce(ya);
        if ((tid & 63) == 63) s_out[bl][o][wq] = red;
      }

      // leave ALL 11 of this iteration's VMEM ops in flight (3 stage + 2 scale + 6 st);
      // everything older (incl. stage/scales for o+1 and prev stores) must be done.
      asm volatile("s_waitcnt vmcnt(11)" ::: "memory");
      __builtin_amdgcn_s_barrier();

      a_cur = a_nx1; b_cur = b_nx1;
      a_nx1 = a_nx2; b_nx1 = b_nx2;
    }
  }

  __syncthreads();   // s_out ds_writes visible
  {
    int bl = tid >> 7;       // 0..3
    int o  = tid & 127;
    float s = s_out[bl][o][0] + s_out[bl][o][1] + s_out[bl][o][2] + s_out[bl][o][3];
    out[(size_t)(b0 + bl) * OUT_DIM + o] = s;
  }
}

extern "C" void kernel_launch(void* const* d_in, const int* in_sizes, int n_in,
                              void* d_out, int out_size, void* d_ws, size_t ws_size,
                              hipStream_t stream) {
  (void)in_sizes; (void)n_in; (void)out_size; (void)ws_size;

  const float* x     = (const float*)d_in[0];
  const float* coef  = (const float*)d_in[1];
  const float* ssp   = (const float*)d_in[2];
  const float* sbase = (const float*)d_in[3];
  // d_in[4] = grid (analytic knots are bit-identical; unused)
  const float* mask  = (const float*)d_in[5];
  const float* bmask = (const float*)d_in[6];

  float* coefT = (float*)d_ws;                                   // 622592 f
  float* At    = coefT + (size_t)OUT_DIM * IN_DIM * NCOEF;       // 32768 f
  float* Bt    = At + (size_t)OUT_DIM * IN_DIM;                  // 32768 f

  float* out        = (float*)d_out;
  float* preacts    = out + (size_t)BATCH * OUT_DIM;
  float* postacts   = preacts + (size_t)BATCH * OUT_DIM * IN_DIM;
  float* postspline = postacts + (size_t)BATCH * OUT_DIM * IN_DIM;

  kan_prep<<<(OUT_DIM * IN_DIM) / 256, 256, 0, stream>>>(coef, ssp, sbase, mask, bmask,
                                                         coefT, At, Bt);
  kan_main<<<BATCH / BT, 512, 0, stream>>>(x, coefT, At, Bt,
                                           out, preacts, postacts, postspline);
}

// Round 10
// 174.006 us; speedup vs baseline: 1.4564x; 1.1896x over previous
//
#include <hip/hip_runtime.h>
#include <math.h>

#define IN_DIM   256
#define OUT_DIM  128
#define NCOEF    19          // NUM + K
#define BATCH    2048
#define BT       4           // batches per main block
#define TILE_F   (IN_DIM * NCOEF)   // 4864 floats per o-tile
#define MAIN_BLOCKS (BATCH / BT)    // 512
#define FILL_BLOCKS (BATCH / 2)     // 1024 (2 batches per fill block)

typedef float f32x4 __attribute__((ext_vector_type(4)));

__device__ __forceinline__ float softplus_f(float v) {
  return (v > 20.0f) ? v : log1pf(expf(v));
}

// async global->LDS, 16B per lane (linear, lane-ordered dest)
__device__ __forceinline__ void load_lds16(const float* g, float* l) {
  __builtin_amdgcn_global_load_lds(
      (const __attribute__((address_space(1))) void*)g,
      (__attribute__((address_space(3))) void*)l,
      16, 0, 0);
}

// stage one o-tile (4864 floats) with 512 threads: 3 x 16B (last partially masked)
__device__ __forceinline__ void stage_tile(const float* src, float* dst, int tid) {
  load_lds16(src + tid * 4,        dst + tid * 4);
  load_lds16(src + 2048 + tid * 4, dst + 2048 + tid * 4);
  if (tid < 192) load_lds16(src + 4096 + tid * 4, dst + 4096 + tid * 4);
}

// ---------------- prep: transform coef (monotonic rows), fold scales, transpose ----
__global__ void kan_prep(const float* __restrict__ coef,
                         const float* __restrict__ ssp,
                         const float* __restrict__ sbase,
                         const float* __restrict__ mask,
                         const float* __restrict__ bmask,
                         float* __restrict__ coefT,   // [o][i][19]
                         float* __restrict__ At,      // [o][i]
                         float* __restrict__ Bt) {    // [o][i]
  int g = blockIdx.x * 256 + threadIdx.x;   // g = o*256 + i
  int o = g >> 8;
  int i = g & 255;
  const float* src = coef + ((size_t)i * OUT_DIM + o) * NCOEF;
  float c[NCOEF];
#pragma unroll
  for (int d = 0; d < NCOEF; ++d) c[d] = src[d];
  if (i < 2) {
    // MONO = ((0,+1),(1,-1)): cumsum(softplus) with direction
    float dir = (i == 0) ? 1.0f : -1.0f;
    float acc = 0.0f;
#pragma unroll
    for (int d = 0; d < NCOEF; ++d) { acc += softplus_f(c[d]); c[d] = dir * acc; }
  }
  float* dst = coefT + (size_t)g * NCOEF;
#pragma unroll
  for (int d = 0; d < NCOEF; ++d) dst[d] = c[d];
  int io = i * OUT_DIM + o;
  float m = mask[io];
  At[g] = m * softplus_f(ssp[io]);
  Bt[g] = m * bmask[io] * sbase[io];
}

// ---------------- wave64 sum via DPP (pure VALU), result in lane 63 ----------------
__device__ __forceinline__ float wave_reduce(float v) {
  int t;
  t = __builtin_amdgcn_update_dpp(0, __float_as_int(v), 0x111, 0xf, 0xf, true); v += __int_as_float(t); // row_shr:1
  t = __builtin_amdgcn_update_dpp(0, __float_as_int(v), 0x112, 0xf, 0xf, true); v += __int_as_float(t); // row_shr:2
  t = __builtin_amdgcn_update_dpp(0, __float_as_int(v), 0x114, 0xf, 0xf, true); v += __int_as_float(t); // row_shr:4
  t = __builtin_amdgcn_update_dpp(0, __float_as_int(v), 0x118, 0xf, 0xf, true); v += __int_as_float(t); // row_shr:8
  t = __builtin_amdgcn_update_dpp(0, __float_as_int(v), 0x142, 0xa, 0xf, true); v += __int_as_float(t); // row_bcast:15 -> rows 1,3
  t = __builtin_amdgcn_update_dpp(0, __float_as_int(v), 0x143, 0xc, 0xf, true); v += __int_as_float(t); // row_bcast:31 -> rows 2,3
  return v;
}

// ---------------- fused: main blocks (bid<512) + preacts-fill blocks ----------------
__global__ __launch_bounds__(512, 6) void kan_main(
    const float* __restrict__ x,
    const float* __restrict__ coefT,
    const float* __restrict__ At,
    const float* __restrict__ Bt,
    float* __restrict__ out,
    float* __restrict__ preacts,
    float* __restrict__ postacts,
    float* __restrict__ postspline) {
  __shared__ __align__(16) float s_coef[2][TILE_F];   // 2 x 19456 B
  __shared__ float s_out[BT][OUT_DIM][4];             // 8 KB

  const int tid = threadIdx.x;
  const int bid = blockIdx.x;

  if (bid >= MAIN_BLOCKS) {
    // ---- fill path: preacts[b,o,:] = x[b,:] — pure dwordx4 nt-store stream,
    // barrier-free, co-resident with main blocks to soak idle store slots.
    const int g    = bid - MAIN_BLOCKS;     // 0..1023
    const int w    = tid >> 6;              // 0..7
    const int lane = tid & 63;
    const int b    = 2 * g + (w >> 2);      // waves 0-3 -> b, 4-7 -> b+1
    const int o0   = (w & 3) * 32;          // 32 o's per wave
    const f32x4 xr = *(const f32x4*)(x + (size_t)b * IN_DIM + lane * 4);
    float* dst = preacts + (((size_t)b * OUT_DIM + o0) * IN_DIM) + lane * 4;
#pragma unroll 8
    for (int k = 0; k < 32; ++k)
      __builtin_nontemporal_store(xr, (f32x4*)(dst + (size_t)k * IN_DIM));
    return;
  }

  // ---------------- main path (R3 structure, preacts removed) ----------------
  const int i    = tid & 255;
  const int bsub = tid >> 8;        // 0..1 -> handles b_local {2*bsub, 2*bsub+1}
  const int wq   = (tid >> 6) & 3;  // wave index within i-group
  const int b0   = bid * BT;

  float xv[2], sl[2], wv[2][4];
  int   wi[2][4];

#pragma unroll
  for (int bb = 0; bb < 2; ++bb) {
    int b = b0 + bsub * 2 + bb;
    float xx = x[(size_t)b * IN_DIM + i];
    xv[bb] = xx;
    sl[bb] = xx / (1.0f + expf(-xx));          // silu

    // locate interval: knots g(a) = -1.375 + 0.125*a  (bit-exact vs reference grid)
    float tpos = (xx + 1.375f) * 8.0f;
    int j = (int)floorf(tpos);
    bool valid = (j >= 0) && (j <= 21);
    int jc = valid ? j : 3;

    // local Cox-de Boor: N[m] = B_{jc-p+m, p}(x)
    float N[4] = {1.0f, 0.0f, 0.0f, 0.0f};
#pragma unroll
    for (int p = 1; p <= 3; ++p) {
      const float inv = (p == 1) ? 8.0f : ((p == 2) ? 4.0f : (8.0f / 3.0f));
      float Np[4] = {0.0f, 0.0f, 0.0f, 0.0f};
#pragma unroll
      for (int m = 0; m < 4; ++m) {
        if (m <= p) {
          float ga = -1.375f + 0.125f * (float)(jc + m - p);
          float v = 0.0f;
          if (m > 0) v += (xx - ga) * inv * N[m - 1];
          if (m < p) v += ((ga + 0.125f * (float)(p + 1)) - xx) * inv * N[m];
          Np[m] = v;
        }
      }
#pragma unroll
      for (int m = 0; m < 4; ++m) N[m] = Np[m];
    }
#pragma unroll
    for (int r = 0; r < 4; ++r) {
      int dr = jc - 3 + r;
      bool ok = valid && (dr >= 0) && (dr <= 18);
      wv[bb][r] = ok ? N[r] : 0.0f;
      wi[bb][r] = i * NCOEF + (ok ? dr : 0);
    }
  }

  // ---- prologue: async-stage o=0 into buffer 0; prefetch scales for o=0
  stage_tile(coefT, &s_coef[0][0], tid);
  float a_cur = At[i];
  float b_cur = Bt[i];
  __syncthreads();   // full drain once in prologue: staged loads landed

  size_t off0 = ((size_t)(b0 + bsub * 2)     * OUT_DIM) * IN_DIM + i;
  size_t off1 = ((size_t)(b0 + bsub * 2 + 1) * OUT_DIM) * IN_DIM + i;

#pragma unroll 2
  for (int o = 0; o < OUT_DIM; ++o) {
    const int cur = o & 1;
    const float* sc = &s_coef[cur][0];

    // ---- issue next tile's async stage FIRST (latency hides under compute)
    if (o + 1 < OUT_DIM)
      stage_tile(coefT + (size_t)(o + 1) * TILE_F, &s_coef[cur ^ 1][0], tid);
    // pin staging issues before everything that follows (keeps them oldest in VMEM FIFO)
    asm volatile("" ::: "memory");

    float a_nxt = 0.0f, b_nxt = 0.0f;
    if (o + 1 < OUT_DIM) {
      a_nxt = At[(o + 1) * IN_DIM + i];
      b_nxt = Bt[(o + 1) * IN_DIM + i];
    }

#pragma unroll
    for (int bb = 0; bb < 2; ++bb) {
      int bl = bsub * 2 + bb;
      float sp = wv[bb][0] * sc[wi[bb][0]]
               + wv[bb][1] * sc[wi[bb][1]]
               + wv[bb][2] * sc[wi[bb][2]]
               + wv[bb][3] * sc[wi[bb][3]];
      float ya = a_cur * sp + b_cur * sl[bb];

      size_t off = (bb == 0 ? off0 : off1) + (size_t)o * IN_DIM;
      __builtin_nontemporal_store(sp, postspline + off);
      __builtin_nontemporal_store(ya, postacts   + off);

      float red = wave_reduce(ya);
      if ((tid & 63) == 63) s_out[bl][o][wq] = red;
    }

    // ---- counted wait: force the 3 lds-loads + 2 scale loads (+prev-iter stores)
    // complete while leaving THIS iteration's 4 stores in flight. Never vmcnt(0).
    asm volatile("s_waitcnt vmcnt(4)" ::: "memory");
    __builtin_amdgcn_s_barrier();

    a_cur = a_nxt;
    b_cur = b_nxt;
  }

  __syncthreads();   // full drain once in epilogue (s_out ds_writes)
  {
    int bl = tid >> 7;       // 0..3
    int o  = tid & 127;
    float s = s_out[bl][o][0] + s_out[bl][o][1] + s_out[bl][o][2] + s_out[bl][o][3];
    out[(size_t)(b0 + bl) * OUT_DIM + o] = s;
  }
}

extern "C" void kernel_launch(void* const* d_in, const int* in_sizes, int n_in,
                              void* d_out, int out_size, void* d_ws, size_t ws_size,
                              hipStream_t stream) {
  (void)in_sizes; (void)n_in; (void)out_size; (void)ws_size;

  const float* x     = (const float*)d_in[0];
  const float* coef  = (const float*)d_in[1];
  const float* ssp   = (const float*)d_in[2];
  const float* sbase = (const float*)d_in[3];
  // d_in[4] = grid (analytic knots are bit-identical; unused)
  const float* mask  = (const float*)d_in[5];
  const float* bmask = (const float*)d_in[6];

  float* coefT = (float*)d_ws;                                   // 622592 f
  float* At    = coefT + (size_t)OUT_DIM * IN_DIM * NCOEF;       // 32768 f
  float* Bt    = At + (size_t)OUT_DIM * IN_DIM;                  // 32768 f

  float* out        = (float*)d_out;
  float* preacts    = out + (size_t)BATCH * OUT_DIM;
  float* postacts   = preacts + (size_t)BATCH * OUT_DIM * IN_DIM;
  float* postspline = postacts + (size_t)BATCH * OUT_DIM * IN_DIM;

  kan_prep<<<(OUT_DIM * IN_DIM) / 256, 256, 0, stream>>>(coef, ssp, sbase, mask, bmask,
                                                         coefT, At, Bt);
  kan_main<<<MAIN_BLOCKS + FILL_BLOCKS, 512, 0, stream>>>(x, coefT, At, Bt,
                                                          out, preacts, postacts, postspline);
}